// Round 1
// baseline (94.118 us; speedup 1.0000x reference)
//
#include <hip/hip_runtime.h>

// DotProductAttention: B=4 H=8 S=2048 D=16, fp32 in/out.
// out = softmax(mask ? -1e10 : 10*tanh(SCALE*(Q K^T))) V
//
// Round 6: FULL FUSION into a single kernel. The 3-kernel pipeline
// (scan -> prep -> hot) spent more on launch serialization + ws round-trips
// than on math (hot-loop floor ~13us vs 93us measured). Now every block:
//   1. re-derives the per-batch key compaction itself (shfl wave-scan +
//      8-wave LDS combine over the 2048-key mask, ~1-2us, idx as ushort[2048]
//      in 4KB LDS),
//   2. gathers its own rounds' K/V fragments straight from global fp32 into
//      double-buffered LDS (identical fragment-major layout to round 4/5),
//      converting to f16 at publish time,
//   3. runs the identical MFMA+softmax inner loop; the bias array is gone --
//      tail pads are killed by a (t*16+i < lim) cndmask folded into the
//      existing fma(c2, w, bias) slot.
// One launch, no workspace, 36KB LDS -> 4 blocks/CU, 8 waves/SIMD.

typedef __fp16 h2 __attribute__((ext_vector_type(2)));
typedef __fp16 h4 __attribute__((ext_vector_type(4)));
typedef float  f4 __attribute__((ext_vector_type(4)));
typedef unsigned short us4 __attribute__((ext_vector_type(4)));

#define SEQ 2048

__device__ __forceinline__ float fast_exp2(float x) {
#if __has_builtin(__builtin_amdgcn_exp2f)
    return __builtin_amdgcn_exp2f(x);
#else
    return exp2f(x);
#endif
}

__device__ __forceinline__ float dot2acc(h2 a, float accv) {
#if __has_builtin(__builtin_amdgcn_fdot2)
    const h2 one = {(__fp16)1.0f, (__fp16)1.0f};
    return __builtin_amdgcn_fdot2(a, one, accv, false);
#else
    return accv + (float)a[0] + (float)a[1];
#endif
}

__global__ __launch_bounds__(512, 8) void attn_fused(
    const float* __restrict__ Qp, const float* __restrict__ Kp,
    const float* __restrict__ Vp, const int* __restrict__ maskp,
    float* __restrict__ out)
{
    __shared__ __align__(16) _Float16 Kbuf[2][4096];      // 16 KB
    __shared__ __align__(16) _Float16 Vbuf[2][4096];      // 16 KB
    __shared__ __align__(16) unsigned short idx16[SEQ];   //  4 KB
    __shared__ int wsum[8];

    const int bid  = blockIdx.x;
    const int bh   = bid >> 5;
    const int qblk = bid & 31;
    const int b    = bh >> 3;
    const int tid  = threadIdx.x;
    const int wave = tid >> 6;
    const int lane = tid & 63;
    const int qt   = wave & 3;   // q-tile
    const int kg   = wave >> 2;  // key-group (tiles 0..7 vs 8..15 of a round)
    const int c    = lane & 15;
    const int g    = lane >> 4;

    const size_t base  = (size_t)bh * (SEQ * 16);
    const int    qbase = qblk * 64 + qt * 16;
    const float  c1 = 1.1047809f;    // 2*SCALE*log2(e)
    const float  c2 = -28.8539008f;  // -20*log2(e)

    // Q fragment (B operand): lane holds c1*Q[qbase+c][4g..4g+3]
    h4 qfrag;
    {
        f4 qv = *(const f4*)(Qp + base + (size_t)(qbase + c) * 16 + 4 * g);
        h2 lo = __builtin_amdgcn_cvt_pkrtz(c1 * qv[0], c1 * qv[1]);
        h2 hi = __builtin_amdgcn_cvt_pkrtz(c1 * qv[2], c1 * qv[3]);
        qfrag[0] = lo[0]; qfrag[1] = lo[1]; qfrag[2] = hi[0]; qfrag[3] = hi[1];
    }

    // ---- phase 0: in-block compaction scan of this batch's mask ----
    int4 mv = *(const int4*)(maskp + (size_t)b * SEQ + tid * 4);
    const int k0 = (mv.x == 0), k1 = (mv.y == 0),
              k2 = (mv.z == 0), k3 = (mv.w == 0);
    const int cnt4 = k0 + k1 + k2 + k3;
    int inc = cnt4;  // inclusive wave prefix
    #pragma unroll
    for (int off = 1; off < 64; off <<= 1) {
        int v = __shfl_up(inc, off);
        if (lane >= off) inc += v;
    }
    *(us4*)&idx16[tid * 4] = (us4){0, 0, 0, 0};  // clamp pad gathers to row 0
    if (lane == 63) wsum[wave] = inc;
    __syncthreads();
    int tot = 0, wpre = 0;
    #pragma unroll
    for (int w = 0; w < 8; ++w) {
        int s = wsum[w];
        if (w < wave) wpre += s;
        tot += s;
    }
    int pos = wpre + inc - cnt4;  // exclusive global prefix
    if (k0) idx16[pos++] = (unsigned short)(tid * 4 + 0);
    if (k1) idx16[pos++] = (unsigned short)(tid * 4 + 1);
    if (k2) idx16[pos++] = (unsigned short)(tid * 4 + 2);
    if (k3) idx16[pos++] = (unsigned short)(tid * 4 + 3);
    __syncthreads();

    int nr = (tot + 255) >> 8;  // rounds of 256 compacted keys
    if (nr == 0) nr = 1;        // degenerate; matches old NaN semantics

    // ---- gather decomposition: 512 threads cover 16 tiles x 64 lanes,
    //      each thread owns lanes u and u+32 of tile tt ----
    const int u  = tid & 31;
    const int tt = tid >> 5;   // tile 0..15
    const int gc = u & 15;     // column
    const int gh = u >> 4;     // 0/1; the +32 lane is gh+2

    const float* Kb = Kp + base;
    const float* Vb = Vp + base;

    const int fs0 = (tt * 64 + u)      * 4;  // halfword slot, lane u
    const int fs1 = (tt * 64 + u + 32) * 4;  // halfword slot, lane u+32

    f4 kA, kB;
    float vA0, vA1, vA2, vA3, vB0, vB1, vB2, vB3;

    // round 0: gather, convert, publish straight into buffer 0
    {
        us4 ra = *(const us4*)&idx16[tt * 16 + 4 * gh];
        us4 rb = *(const us4*)&idx16[tt * 16 + 4 * gh + 8];
        const int krow = idx16[tt * 16 + gc];
        const float* kr = Kb + (size_t)krow * 16;
        f4 ka_ = *(const f4*)(kr + 4 * gh);
        f4 kb_ = *(const f4*)(kr + 4 * gh + 8);
        float a0 = Vb[(size_t)ra[0] * 16 + gc];
        float a1 = Vb[(size_t)ra[1] * 16 + gc];
        float a2 = Vb[(size_t)ra[2] * 16 + gc];
        float a3 = Vb[(size_t)ra[3] * 16 + gc];
        float b0 = Vb[(size_t)rb[0] * 16 + gc];
        float b1 = Vb[(size_t)rb[1] * 16 + gc];
        float b2 = Vb[(size_t)rb[2] * 16 + gc];
        float b3 = Vb[(size_t)rb[3] * 16 + gc];
        h2 x0 = __builtin_amdgcn_cvt_pkrtz(ka_[0], ka_[1]);
        h2 x1 = __builtin_amdgcn_cvt_pkrtz(ka_[2], ka_[3]);
        h4 kha; kha[0] = x0[0]; kha[1] = x0[1]; kha[2] = x1[0]; kha[3] = x1[1];
        *(h4*)&Kbuf[0][fs0] = kha;
        h2 y0 = __builtin_amdgcn_cvt_pkrtz(kb_[0], kb_[1]);
        h2 y1 = __builtin_amdgcn_cvt_pkrtz(kb_[2], kb_[3]);
        h4 khb; khb[0] = y0[0]; khb[1] = y0[1]; khb[2] = y1[0]; khb[3] = y1[1];
        *(h4*)&Kbuf[0][fs1] = khb;
        h2 p0 = __builtin_amdgcn_cvt_pkrtz(a0, a1);
        h2 p1 = __builtin_amdgcn_cvt_pkrtz(a2, a3);
        h4 vha; vha[0] = p0[0]; vha[1] = p0[1]; vha[2] = p1[0]; vha[3] = p1[1];
        *(h4*)&Vbuf[0][fs0] = vha;
        h2 q0 = __builtin_amdgcn_cvt_pkrtz(b0, b1);
        h2 q1 = __builtin_amdgcn_cvt_pkrtz(b2, b3);
        h4 vhb; vhb[0] = q0[0]; vhb[1] = q0[1]; vhb[2] = q1[0]; vhb[3] = q1[1];
        *(h4*)&Vbuf[0][fs1] = vhb;
    }
    // prefetch round 1 into registers (or re-read round 0 if nr==1; unused)
    {
        const int r1 = (nr > 1) ? 1 : 0;
        const int ib = r1 * 256 + tt * 16;
        us4 ra = *(const us4*)&idx16[ib + 4 * gh];
        us4 rb = *(const us4*)&idx16[ib + 4 * gh + 8];
        const int krow = idx16[ib + gc];
        const float* kr = Kb + (size_t)krow * 16;
        kA = *(const f4*)(kr + 4 * gh);
        kB = *(const f4*)(kr + 4 * gh + 8);
        vA0 = Vb[(size_t)ra[0] * 16 + gc];
        vA1 = Vb[(size_t)ra[1] * 16 + gc];
        vA2 = Vb[(size_t)ra[2] * 16 + gc];
        vA3 = Vb[(size_t)ra[3] * 16 + gc];
        vB0 = Vb[(size_t)rb[0] * 16 + gc];
        vB1 = Vb[(size_t)rb[1] * 16 + gc];
        vB2 = Vb[(size_t)rb[2] * 16 + gc];
        vB3 = Vb[(size_t)rb[3] * 16 + gc];
    }
    __syncthreads();

    f4 acc = {0.f, 0.f, 0.f, 0.f};
    float dsum = 0.f;

    for (int r = 0; r < nr; ++r) {
        const int cb = r & 1, nb = cb ^ 1;
        if (r + 1 < nr) {  // publish prefetched round r+1 (convert + ds_write)
            h2 x0 = __builtin_amdgcn_cvt_pkrtz(kA[0], kA[1]);
            h2 x1 = __builtin_amdgcn_cvt_pkrtz(kA[2], kA[3]);
            h4 kha; kha[0] = x0[0]; kha[1] = x0[1]; kha[2] = x1[0]; kha[3] = x1[1];
            *(h4*)&Kbuf[nb][fs0] = kha;
            h2 y0 = __builtin_amdgcn_cvt_pkrtz(kB[0], kB[1]);
            h2 y1 = __builtin_amdgcn_cvt_pkrtz(kB[2], kB[3]);
            h4 khb; khb[0] = y0[0]; khb[1] = y0[1]; khb[2] = y1[0]; khb[3] = y1[1];
            *(h4*)&Kbuf[nb][fs1] = khb;
            h2 p0 = __builtin_amdgcn_cvt_pkrtz(vA0, vA1);
            h2 p1 = __builtin_amdgcn_cvt_pkrtz(vA2, vA3);
            h4 vha; vha[0] = p0[0]; vha[1] = p0[1]; vha[2] = p1[0]; vha[3] = p1[1];
            *(h4*)&Vbuf[nb][fs0] = vha;
            h2 q0 = __builtin_amdgcn_cvt_pkrtz(vB0, vB1);
            h2 q1 = __builtin_amdgcn_cvt_pkrtz(vB2, vB3);
            h4 vhb; vhb[0] = q0[0]; vhb[1] = q0[1]; vhb[2] = q1[0]; vhb[3] = q1[1];
            *(h4*)&Vbuf[nb][fs1] = vhb;
        }
        if (r + 2 < nr) {  // issue gathers for round r+2
            const int ib = (r + 2) * 256 + tt * 16;
            us4 ra = *(const us4*)&idx16[ib + 4 * gh];
            us4 rb = *(const us4*)&idx16[ib + 4 * gh + 8];
            const int krow = idx16[ib + gc];
            const float* kr = Kb + (size_t)krow * 16;
            kA = *(const f4*)(kr + 4 * gh);
            kB = *(const f4*)(kr + 4 * gh + 8);
            vA0 = Vb[(size_t)ra[0] * 16 + gc];
            vA1 = Vb[(size_t)ra[1] * 16 + gc];
            vA2 = Vb[(size_t)ra[2] * 16 + gc];
            vA3 = Vb[(size_t)ra[3] * 16 + gc];
            vB0 = Vb[(size_t)rb[0] * 16 + gc];
            vB1 = Vb[(size_t)rb[1] * 16 + gc];
            vB2 = Vb[(size_t)rb[2] * 16 + gc];
            vB3 = Vb[(size_t)rb[3] * 16 + gc];
        }

        const _Float16* Kc = &Kbuf[cb][kg * 2048];
        const _Float16* Vc = &Vbuf[cb][kg * 2048];
        // key position of element (t,i) is r*256 + kg*128 + t*16 + 4g + i;
        // pad iff t*16+i >= lim. Non-tail rounds: lim > 115+3, compare is moot.
        const int lim = tot - r * 256 - kg * 128 - 4 * g;

        #pragma unroll
        for (int t = 0; t < 8; ++t) {
            h4 afrag = *(const h4*)(Kc + t * 256 + lane * 4);
            f4 s = __builtin_amdgcn_mfma_f32_16x16x16f16(
                afrag, qfrag, (f4){0.f, 0.f, 0.f, 0.f}, 0, 0, 0);

            float p[4];
            #pragma unroll
            for (int i = 0; i < 4; ++i) {
                float tv = fast_exp2(s[i]);
                float w  = __builtin_amdgcn_rcpf(1.0f + tv);
                float bsel = (t * 16 + i < lim) ? 0.0f : -1.0e30f;
                p[i] = fast_exp2(__builtin_fmaf(c2, w, bsel));
            }
            h2 plo = __builtin_amdgcn_cvt_pkrtz(p[0], p[1]);
            h2 phi = __builtin_amdgcn_cvt_pkrtz(p[2], p[3]);
            dsum = dot2acc(plo, dsum);
            dsum = dot2acc(phi, dsum);
            h4 pf; pf[0] = plo[0]; pf[1] = plo[1]; pf[2] = phi[0]; pf[3] = phi[1];

            h4 vfrag = *(const h4*)(Vc + t * 256 + lane * 4);
            acc = __builtin_amdgcn_mfma_f32_16x16x16f16(pf, vfrag, acc, 0, 0, 0);
        }
        __syncthreads();
    }

    // denom over this key-group for q=qbase+c, on all lanes of the wave
    dsum += __shfl_xor(dsum, 16);
    dsum += __shfl_xor(dsum, 32);

    // cross-key-group combine through LDS (reuse Kbuf; last barrier done)
    float* ex = (float*)&Kbuf[0][0];
    const int slot = (qt * 64 + lane) * 5;
    if (kg == 1) {
        ex[slot + 0] = acc[0]; ex[slot + 1] = acc[1];
        ex[slot + 2] = acc[2]; ex[slot + 3] = acc[3];
        ex[slot + 4] = dsum;
    }
    __syncthreads();
    if (kg == 0) {
        const float dT = dsum + ex[slot + 4];
        #pragma unroll
        for (int i = 0; i < 4; ++i) {
            const float denom = __shfl(dT, 4 * g + i);
            out[base + (size_t)(qbase + 4 * g + i) * 16 + c] =
                (acc[i] + ex[slot + i]) / denom;
        }
    }
}

extern "C" void kernel_launch(void* const* d_in, const int* in_sizes, int n_in,
                              void* d_out, int out_size, void* d_ws, size_t ws_size,
                              hipStream_t stream) {
    const float* Q    = (const float*)d_in[0];
    const float* K    = (const float*)d_in[1];
    const float* V    = (const float*)d_in[2];
    const int*   mask = (const int*)d_in[3];
    float* out = (float*)d_out;
    attn_fused<<<dim3(1024), dim3(512), 0, stream>>>(Q, K, V, mask, out);
}

// Round 2
// 90.916 us; speedup vs baseline: 1.0352x; 1.0352x over previous
//
#include <hip/hip_runtime.h>

// DotProductAttention: B=4 H=8 S=2048 D=16, fp32 in/out.
// out = softmax(mask ? -1e10 : 10*tanh(SCALE*(Q K^T))) V
//
// Round 7: measured floor analysis — dur_us ~94 is ~2x41.5us harness 256MB
// workspace re-poison fills (at HBM write peak) + ~11us kernel. Only the
// kernel part is controllable. It is VALU/trans-bound (3 transcendentals
// per (q,k) pair; floor ~5.2us). This round removes the two overheads above
// the trans floor:
//   1. 128 queries/block (512 blocks): halves per-block staging redundancy
//      (scan + gather + f32->f16 convert were redone by 32 blocks per bh,
//      now 16) and halves K/V LDS reads (one afrag/vfrag feeds two q-tiles).
//      __launch_bounds__(512,4) for the doubled accumulator state.
//   2. Tail peel: non-final rounds drop the pad cndmask; the final round
//      clamps its tile loop to ceil(rem/16) instead of always 8 — when
//      nr==5 (tot>1024, ~50% of batches) the old code burned a ~95%-pad
//      round of full MFMA+softmax.
// Everything else (in-block compaction scan, fragment-major double-buffered
// LDS, depth-2 register prefetch, 1 barrier/round) carried from round 6.

typedef __fp16 h2 __attribute__((ext_vector_type(2)));
typedef __fp16 h4 __attribute__((ext_vector_type(4)));
typedef float  f4 __attribute__((ext_vector_type(4)));
typedef unsigned short us4 __attribute__((ext_vector_type(4)));

#define SEQ 2048

__device__ __forceinline__ float fast_exp2(float x) {
#if __has_builtin(__builtin_amdgcn_exp2f)
    return __builtin_amdgcn_exp2f(x);
#else
    return exp2f(x);
#endif
}

__device__ __forceinline__ float dot2acc(h2 a, float accv) {
#if __has_builtin(__builtin_amdgcn_fdot2)
    const h2 one = {(__fp16)1.0f, (__fp16)1.0f};
    return __builtin_amdgcn_fdot2(a, one, accv, false);
#else
    return accv + (float)a[0] + (float)a[1];
#endif
}

// softmax weights for 4 scores; bsel pre-selected (0 or -1e30 per element)
__device__ __forceinline__ h4 prob4(f4 s, f4 bsel, float c2, float& dsum) {
    float p[4];
    #pragma unroll
    for (int i = 0; i < 4; ++i) {
        float tv = fast_exp2(s[i]);
        float w  = __builtin_amdgcn_rcpf(1.0f + tv);
        p[i] = fast_exp2(__builtin_fmaf(c2, w, bsel[i]));
    }
    h2 plo = __builtin_amdgcn_cvt_pkrtz(p[0], p[1]);
    h2 phi = __builtin_amdgcn_cvt_pkrtz(p[2], p[3]);
    dsum = dot2acc(plo, dsum);
    dsum = dot2acc(phi, dsum);
    h4 pf; pf[0] = plo[0]; pf[1] = plo[1]; pf[2] = phi[0]; pf[3] = phi[1];
    return pf;
}

__global__ __launch_bounds__(512, 4) void attn_fused(
    const float* __restrict__ Qp, const float* __restrict__ Kp,
    const float* __restrict__ Vp, const int* __restrict__ maskp,
    float* __restrict__ out)
{
    __shared__ __align__(16) _Float16 Kbuf[2][4096];      // 16 KB
    __shared__ __align__(16) _Float16 Vbuf[2][4096];      // 16 KB
    __shared__ __align__(16) unsigned short idx16[SEQ];   //  4 KB
    __shared__ int wsum[8];

    const int bid  = blockIdx.x;
    const int bh   = bid >> 4;   // 32 bh
    const int qblk = bid & 15;   // 16 q-blocks of 128 queries
    const int b    = bh >> 3;
    const int tid  = threadIdx.x;
    const int wave = tid >> 6;
    const int lane = tid & 63;
    const int qt   = wave & 3;   // q-tile pair: handles qt and qt+4
    const int kg   = wave >> 2;  // key-group (tiles 0..7 vs 8..15 of a round)
    const int c    = lane & 15;
    const int g    = lane >> 4;

    const size_t base  = (size_t)bh * (SEQ * 16);
    const int    qb0   = qblk * 128 + qt * 16;   // first q-tile row
    const int    qb1   = qb0 + 64;               // second q-tile row
    const float  c1 = 1.1047809f;    // 2*SCALE*log2(e)
    const float  c2 = -28.8539008f;  // -20*log2(e)

    // Q fragments (B operand): lane holds c1*Q[qb+c][4g..4g+3]
    h4 qfrag0, qfrag1;
    {
        f4 qv = *(const f4*)(Qp + base + (size_t)(qb0 + c) * 16 + 4 * g);
        h2 lo = __builtin_amdgcn_cvt_pkrtz(c1 * qv[0], c1 * qv[1]);
        h2 hi = __builtin_amdgcn_cvt_pkrtz(c1 * qv[2], c1 * qv[3]);
        qfrag0[0] = lo[0]; qfrag0[1] = lo[1]; qfrag0[2] = hi[0]; qfrag0[3] = hi[1];
        f4 qw = *(const f4*)(Qp + base + (size_t)(qb1 + c) * 16 + 4 * g);
        h2 l2 = __builtin_amdgcn_cvt_pkrtz(c1 * qw[0], c1 * qw[1]);
        h2 h2_ = __builtin_amdgcn_cvt_pkrtz(c1 * qw[2], c1 * qw[3]);
        qfrag1[0] = l2[0]; qfrag1[1] = l2[1]; qfrag1[2] = h2_[0]; qfrag1[3] = h2_[1];
    }

    // ---- phase 0: in-block compaction scan of this batch's mask ----
    int4 mv = *(const int4*)(maskp + (size_t)b * SEQ + tid * 4);
    const int k0 = (mv.x == 0), k1 = (mv.y == 0),
              k2 = (mv.z == 0), k3 = (mv.w == 0);
    const int cnt4 = k0 + k1 + k2 + k3;
    int inc = cnt4;  // inclusive wave prefix
    #pragma unroll
    for (int off = 1; off < 64; off <<= 1) {
        int v = __shfl_up(inc, off);
        if (lane >= off) inc += v;
    }
    *(us4*)&idx16[tid * 4] = (us4){0, 0, 0, 0};  // clamp pad gathers to row 0
    if (lane == 63) wsum[wave] = inc;
    __syncthreads();
    int tot = 0, wpre = 0;
    #pragma unroll
    for (int w = 0; w < 8; ++w) {
        int s = wsum[w];
        if (w < wave) wpre += s;
        tot += s;
    }
    int pos = wpre + inc - cnt4;  // exclusive global prefix
    if (k0) idx16[pos++] = (unsigned short)(tid * 4 + 0);
    if (k1) idx16[pos++] = (unsigned short)(tid * 4 + 1);
    if (k2) idx16[pos++] = (unsigned short)(tid * 4 + 2);
    if (k3) idx16[pos++] = (unsigned short)(tid * 4 + 3);
    __syncthreads();

    int nr = (tot + 255) >> 8;  // rounds of 256 compacted keys
    if (nr == 0) nr = 1;        // degenerate; matches old NaN semantics

    // ---- gather decomposition: 512 threads cover 16 tiles x 64 lanes,
    //      each thread owns lanes u and u+32 of tile tt ----
    const int u  = tid & 31;
    const int tt = tid >> 5;   // tile 0..15
    const int gc = u & 15;     // column
    const int gh = u >> 4;     // 0/1; the +32 lane is gh+2

    const float* Kb = Kp + base;
    const float* Vb = Vp + base;

    const int fs0 = (tt * 64 + u)      * 4;  // halfword slot, lane u
    const int fs1 = (tt * 64 + u + 32) * 4;  // halfword slot, lane u+32

    f4 kA, kB;
    float vA0, vA1, vA2, vA3, vB0, vB1, vB2, vB3;

    // round 0: gather, convert, publish straight into buffer 0
    {
        us4 ra = *(const us4*)&idx16[tt * 16 + 4 * gh];
        us4 rb = *(const us4*)&idx16[tt * 16 + 4 * gh + 8];
        const int krow = idx16[tt * 16 + gc];
        const float* kr = Kb + (size_t)krow * 16;
        f4 ka_ = *(const f4*)(kr + 4 * gh);
        f4 kb_ = *(const f4*)(kr + 4 * gh + 8);
        float a0 = Vb[(size_t)ra[0] * 16 + gc];
        float a1 = Vb[(size_t)ra[1] * 16 + gc];
        float a2 = Vb[(size_t)ra[2] * 16 + gc];
        float a3 = Vb[(size_t)ra[3] * 16 + gc];
        float b0 = Vb[(size_t)rb[0] * 16 + gc];
        float b1 = Vb[(size_t)rb[1] * 16 + gc];
        float b2 = Vb[(size_t)rb[2] * 16 + gc];
        float b3 = Vb[(size_t)rb[3] * 16 + gc];
        h2 x0 = __builtin_amdgcn_cvt_pkrtz(ka_[0], ka_[1]);
        h2 x1 = __builtin_amdgcn_cvt_pkrtz(ka_[2], ka_[3]);
        h4 kha; kha[0] = x0[0]; kha[1] = x0[1]; kha[2] = x1[0]; kha[3] = x1[1];
        *(h4*)&Kbuf[0][fs0] = kha;
        h2 y0 = __builtin_amdgcn_cvt_pkrtz(kb_[0], kb_[1]);
        h2 y1 = __builtin_amdgcn_cvt_pkrtz(kb_[2], kb_[3]);
        h4 khb; khb[0] = y0[0]; khb[1] = y0[1]; khb[2] = y1[0]; khb[3] = y1[1];
        *(h4*)&Kbuf[0][fs1] = khb;
        h2 p0 = __builtin_amdgcn_cvt_pkrtz(a0, a1);
        h2 p1 = __builtin_amdgcn_cvt_pkrtz(a2, a3);
        h4 vha; vha[0] = p0[0]; vha[1] = p0[1]; vha[2] = p1[0]; vha[3] = p1[1];
        *(h4*)&Vbuf[0][fs0] = vha;
        h2 q0 = __builtin_amdgcn_cvt_pkrtz(b0, b1);
        h2 q1 = __builtin_amdgcn_cvt_pkrtz(b2, b3);
        h4 vhb; vhb[0] = q0[0]; vhb[1] = q0[1]; vhb[2] = q1[0]; vhb[3] = q1[1];
        *(h4*)&Vbuf[0][fs1] = vhb;
    }
    // prefetch round 1 into registers (or re-read round 0 if nr==1; unused)
    {
        const int r1 = (nr > 1) ? 1 : 0;
        const int ib = r1 * 256 + tt * 16;
        us4 ra = *(const us4*)&idx16[ib + 4 * gh];
        us4 rb = *(const us4*)&idx16[ib + 4 * gh + 8];
        const int krow = idx16[ib + gc];
        const float* kr = Kb + (size_t)krow * 16;
        kA = *(const f4*)(kr + 4 * gh);
        kB = *(const f4*)(kr + 4 * gh + 8);
        vA0 = Vb[(size_t)ra[0] * 16 + gc];
        vA1 = Vb[(size_t)ra[1] * 16 + gc];
        vA2 = Vb[(size_t)ra[2] * 16 + gc];
        vA3 = Vb[(size_t)ra[3] * 16 + gc];
        vB0 = Vb[(size_t)rb[0] * 16 + gc];
        vB1 = Vb[(size_t)rb[1] * 16 + gc];
        vB2 = Vb[(size_t)rb[2] * 16 + gc];
        vB3 = Vb[(size_t)rb[3] * 16 + gc];
    }
    __syncthreads();

    f4 acc0 = {0.f, 0.f, 0.f, 0.f}, acc1 = {0.f, 0.f, 0.f, 0.f};
    float dsum0 = 0.f, dsum1 = 0.f;

    for (int r = 0; r < nr; ++r) {
        const int cb = r & 1, nb = cb ^ 1;
        if (r + 1 < nr) {  // publish prefetched round r+1 (convert + ds_write)
            h2 x0 = __builtin_amdgcn_cvt_pkrtz(kA[0], kA[1]);
            h2 x1 = __builtin_amdgcn_cvt_pkrtz(kA[2], kA[3]);
            h4 kha; kha[0] = x0[0]; kha[1] = x0[1]; kha[2] = x1[0]; kha[3] = x1[1];
            *(h4*)&Kbuf[nb][fs0] = kha;
            h2 y0 = __builtin_amdgcn_cvt_pkrtz(kB[0], kB[1]);
            h2 y1 = __builtin_amdgcn_cvt_pkrtz(kB[2], kB[3]);
            h4 khb; khb[0] = y0[0]; khb[1] = y0[1]; khb[2] = y1[0]; khb[3] = y1[1];
            *(h4*)&Kbuf[nb][fs1] = khb;
            h2 p0 = __builtin_amdgcn_cvt_pkrtz(vA0, vA1);
            h2 p1 = __builtin_amdgcn_cvt_pkrtz(vA2, vA3);
            h4 vha; vha[0] = p0[0]; vha[1] = p0[1]; vha[2] = p1[0]; vha[3] = p1[1];
            *(h4*)&Vbuf[nb][fs0] = vha;
            h2 q0 = __builtin_amdgcn_cvt_pkrtz(vB0, vB1);
            h2 q1 = __builtin_amdgcn_cvt_pkrtz(vB2, vB3);
            h4 vhb; vhb[0] = q0[0]; vhb[1] = q0[1]; vhb[2] = q1[0]; vhb[3] = q1[1];
            *(h4*)&Vbuf[nb][fs1] = vhb;
        }
        if (r + 2 < nr) {  // issue gathers for round r+2
            const int ib = (r + 2) * 256 + tt * 16;
            us4 ra = *(const us4*)&idx16[ib + 4 * gh];
            us4 rb = *(const us4*)&idx16[ib + 4 * gh + 8];
            const int krow = idx16[ib + gc];
            const float* kr = Kb + (size_t)krow * 16;
            kA = *(const f4*)(kr + 4 * gh);
            kB = *(const f4*)(kr + 4 * gh + 8);
            vA0 = Vb[(size_t)ra[0] * 16 + gc];
            vA1 = Vb[(size_t)ra[1] * 16 + gc];
            vA2 = Vb[(size_t)ra[2] * 16 + gc];
            vA3 = Vb[(size_t)ra[3] * 16 + gc];
            vB0 = Vb[(size_t)rb[0] * 16 + gc];
            vB1 = Vb[(size_t)rb[1] * 16 + gc];
            vB2 = Vb[(size_t)rb[2] * 16 + gc];
            vB3 = Vb[(size_t)rb[3] * 16 + gc];
        }

        const _Float16* Kc = &Kbuf[cb][kg * 2048];
        const _Float16* Vc = &Vbuf[cb][kg * 2048];

        if (r + 1 < nr) {
            // full round: no pads possible (r*256+256 <= (nr-1)*256 < tot)
            const f4 z = {0.f, 0.f, 0.f, 0.f};
            #pragma unroll
            for (int t = 0; t < 8; ++t) {
                h4 afrag = *(const h4*)(Kc + t * 256 + lane * 4);
                f4 s0 = __builtin_amdgcn_mfma_f32_16x16x16f16(
                    afrag, qfrag0, (f4){0.f, 0.f, 0.f, 0.f}, 0, 0, 0);
                f4 s1 = __builtin_amdgcn_mfma_f32_16x16x16f16(
                    afrag, qfrag1, (f4){0.f, 0.f, 0.f, 0.f}, 0, 0, 0);
                h4 pf0 = prob4(s0, z, c2, dsum0);
                h4 pf1 = prob4(s1, z, c2, dsum1);
                h4 vfrag = *(const h4*)(Vc + t * 256 + lane * 4);
                acc0 = __builtin_amdgcn_mfma_f32_16x16x16f16(pf0, vfrag, acc0, 0, 0, 0);
                acc1 = __builtin_amdgcn_mfma_f32_16x16x16f16(pf1, vfrag, acc1, 0, 0, 0);
            }
        } else {
            // tail round: clamp tile count, mask pad elements
            const int rem  = tot - r * 256 - kg * 128;  // keys for this group
            int tcnt = (rem <= 0) ? 0 : ((rem + 15) >> 4);
            if (tcnt > 8) tcnt = 8;
            const int lim = rem - 4 * g;  // pad iff t*16+i >= lim
            for (int t = 0; t < tcnt; ++t) {
                h4 afrag = *(const h4*)(Kc + t * 256 + lane * 4);
                f4 s0 = __builtin_amdgcn_mfma_f32_16x16x16f16(
                    afrag, qfrag0, (f4){0.f, 0.f, 0.f, 0.f}, 0, 0, 0);
                f4 s1 = __builtin_amdgcn_mfma_f32_16x16x16f16(
                    afrag, qfrag1, (f4){0.f, 0.f, 0.f, 0.f}, 0, 0, 0);
                f4 bsel;
                #pragma unroll
                for (int i = 0; i < 4; ++i)
                    bsel[i] = (t * 16 + i < lim) ? 0.0f : -1.0e30f;
                h4 pf0 = prob4(s0, bsel, c2, dsum0);
                h4 pf1 = prob4(s1, bsel, c2, dsum1);
                h4 vfrag = *(const h4*)(Vc + t * 256 + lane * 4);
                acc0 = __builtin_amdgcn_mfma_f32_16x16x16f16(pf0, vfrag, acc0, 0, 0, 0);
                acc1 = __builtin_amdgcn_mfma_f32_16x16x16f16(pf1, vfrag, acc1, 0, 0, 0);
            }
        }
        __syncthreads();
    }

    // denom over this key-group for q=qb+c, on all lanes of the wave
    dsum0 += __shfl_xor(dsum0, 16);
    dsum0 += __shfl_xor(dsum0, 32);
    dsum1 += __shfl_xor(dsum1, 16);
    dsum1 += __shfl_xor(dsum1, 32);

    // cross-key-group combine through LDS (reuse Kbuf; last barrier done)
    // two slot sets: tile-set 0 (qt) and tile-set 1 (qt+4); 10.25 KB < 16 KB
    float* ex = (float*)&Kbuf[0][0];
    const int slot0 = ((qt)     * 64 + lane) * 5;
    const int slot1 = ((qt + 4) * 64 + lane) * 5;
    if (kg == 1) {
        ex[slot0 + 0] = acc0[0]; ex[slot0 + 1] = acc0[1];
        ex[slot0 + 2] = acc0[2]; ex[slot0 + 3] = acc0[3];
        ex[slot0 + 4] = dsum0;
        ex[slot1 + 0] = acc1[0]; ex[slot1 + 1] = acc1[1];
        ex[slot1 + 2] = acc1[2]; ex[slot1 + 3] = acc1[3];
        ex[slot1 + 4] = dsum1;
    }
    __syncthreads();
    if (kg == 0) {
        const float dT0 = dsum0 + ex[slot0 + 4];
        const float dT1 = dsum1 + ex[slot1 + 4];
        #pragma unroll
        for (int i = 0; i < 4; ++i) {
            const float den0 = __shfl(dT0, 4 * g + i);
            out[base + (size_t)(qb0 + 4 * g + i) * 16 + c] =
                (acc0[i] + ex[slot0 + i]) / den0;
            const float den1 = __shfl(dT1, 4 * g + i);
            out[base + (size_t)(qb1 + 4 * g + i) * 16 + c] =
                (acc1[i] + ex[slot1 + i]) / den1;
        }
    }
}

extern "C" void kernel_launch(void* const* d_in, const int* in_sizes, int n_in,
                              void* d_out, int out_size, void* d_ws, size_t ws_size,
                              hipStream_t stream) {
    const float* Q    = (const float*)d_in[0];
    const float* K    = (const float*)d_in[1];
    const float* V    = (const float*)d_in[2];
    const int*   mask = (const int*)d_in[3];
    float* out = (float*)d_out;
    attn_fused<<<dim3(512), dim3(512), 0, stream>>>(Q, K, V, mask, out);
}